// Round 4
// baseline (341.946 us; speedup 1.0000x reference)
//
#include <hip/hip_runtime.h>
#include <math.h>

#define NROWS 200000
#define DCOLS 512
#define NC 3
#define SGRID 2048
#define NH (SGRID * 2)   // rows advanced per grid step (128 threads/row)
#define CGRID 2048

typedef float f4 __attribute__((ext_vector_type(4)));

__device__ __forceinline__ float elu1(float x) {
    return x > 0.0f ? x : __expf(x) - 1.0f;
}

__global__ void zero_sums(float* sums) {
    int t = blockIdx.x * blockDim.x + threadIdx.x;
    if (t < NC * DCOLS) sums[t] = 0.0f;
}

// Stream-copy-shaped segment sum: 128 threads own one row slice (col fixed
// per thread), grid-stride by NH rows, unroll x2 with both nontemporal
// float4 loads issued before the (wave-uniform) label branches.
// nt keeps the once-read `feature` from evicting `seq` out of L3.
__global__ __launch_bounds__(256) void segsum_kernel(
        const float* __restrict__ feature, const float* __restrict__ seq,
        const float* __restrict__ weight, const int* __restrict__ labels,
        const int* __restrict__ train, float* __restrict__ sums) {
    const int t = threadIdx.x;
    const int c4 = (t & 127) << 2;           // column base (4 floats)
    const int h  = t >> 7;                   // wave-uniform (64 | 256-block)
    const int halfid = blockIdx.x * 2 + h;   // starting row
    const int tr = train[0];
    f4 w = (f4)(0.f);
    if (tr) w = *(const f4*)(weight + c4);
    const float* __restrict__ src = tr ? seq : feature;
    f4 a0 = (f4)(0.f), a1 = (f4)(0.f), a2 = (f4)(0.f);

    const float* pbase = src + c4;
    int row = halfid;
    for (; row + NH < NROWS; row += 2 * NH) {
        int la = labels[row];
        int lb = labels[row + NH];
        f4 xa = __builtin_nontemporal_load((const f4*)(pbase + (size_t)row * DCOLS));
        f4 xb = __builtin_nontemporal_load((const f4*)(pbase + (size_t)(row + NH) * DCOLS));
        if (tr) {
            xa.x = elu1(w.x * xa.x); xa.y = elu1(w.y * xa.y);
            xa.z = elu1(w.z * xa.z); xa.w = elu1(w.w * xa.w);
            xb.x = elu1(w.x * xb.x); xb.y = elu1(w.y * xb.y);
            xb.z = elu1(w.z * xb.z); xb.w = elu1(w.w * xb.w);
        }
        if (la == 0) a0 += xa; else if (la == 1) a1 += xa; else a2 += xa;
        if (lb == 0) a0 += xb; else if (lb == 1) a1 += xb; else a2 += xb;
    }
    if (row < NROWS) {
        int la = labels[row];
        f4 xa = __builtin_nontemporal_load((const f4*)(pbase + (size_t)row * DCOLS));
        if (tr) {
            xa.x = elu1(w.x * xa.x); xa.y = elu1(w.y * xa.y);
            xa.z = elu1(w.z * xa.z); xa.w = elu1(w.w * xa.w);
        }
        if (la == 0) a0 += xa; else if (la == 1) a1 += xa; else a2 += xa;
    }

    // halves-reduce in LDS, then one atomicAdd per (class,col) per block
    __shared__ float red[NC][128][4];
    if (h == 1) {
        const int c = t & 127;
        *(f4*)red[0][c] = a0;
        *(f4*)red[1][c] = a1;
        *(f4*)red[2][c] = a2;
    }
    __syncthreads();
    if (h == 0) {
        const int c = t;
        a0 += *(const f4*)red[0][c];
        a1 += *(const f4*)red[1][c];
        a2 += *(const f4*)red[2][c];
        atomicAdd(&sums[0 * DCOLS + c4 + 0], a0.x);
        atomicAdd(&sums[0 * DCOLS + c4 + 1], a0.y);
        atomicAdd(&sums[0 * DCOLS + c4 + 2], a0.z);
        atomicAdd(&sums[0 * DCOLS + c4 + 3], a0.w);
        atomicAdd(&sums[1 * DCOLS + c4 + 0], a1.x);
        atomicAdd(&sums[1 * DCOLS + c4 + 1], a1.y);
        atomicAdd(&sums[1 * DCOLS + c4 + 2], a1.z);
        atomicAdd(&sums[1 * DCOLS + c4 + 3], a1.w);
        atomicAdd(&sums[2 * DCOLS + c4 + 0], a2.x);
        atomicAdd(&sums[2 * DCOLS + c4 + 1], a2.y);
        atomicAdd(&sums[2 * DCOLS + c4 + 2], a2.z);
        atomicAdd(&sums[2 * DCOLS + c4 + 3], a2.w);
    }
}

// ave = sums / (N/2); an[c] = ||ave[c]||. Single block.
__global__ __launch_bounds__(256) void ave_norm_kernel(
        const float* __restrict__ sums, float* __restrict__ ave,
        float* __restrict__ an) {
    __shared__ float red[4];
    const int t = threadIdx.x, lane = t & 63, wv = t >> 6;
    const float inv = 1.0f / (float)(NROWS / 2);
    for (int c = 0; c < NC; ++c) {
        float p = 0.0f;
        for (int j = t; j < DCOLS; j += 256) {
            float v = sums[c * DCOLS + j] * inv;
            ave[c * DCOLS + j] = v;
            p += v * v;
        }
        for (int o = 32; o; o >>= 1) p += __shfl_xor(p, o);
        if (lane == 0) red[wv] = p;
        __syncthreads();
        if (t == 0) an[c] = sqrtf(red[0] + red[1] + red[2] + red[3]);
        __syncthreads();
    }
}

__device__ __forceinline__ void proc4(float4 s, float4 w,
                                      float4 a0, float4 a1, float4 a2,
                                      float& rn2, float& d0, float& d1, float& d2) {
    float r;
    r = elu1(w.x * s.x); rn2 = fmaf(r, r, rn2); d0 = fmaf(r, a0.x, d0); d1 = fmaf(r, a1.x, d1); d2 = fmaf(r, a2.x, d2);
    r = elu1(w.y * s.y); rn2 = fmaf(r, r, rn2); d0 = fmaf(r, a0.y, d0); d1 = fmaf(r, a1.y, d1); d2 = fmaf(r, a2.y, d2);
    r = elu1(w.z * s.z); rn2 = fmaf(r, r, rn2); d0 = fmaf(r, a0.z, d0); d1 = fmaf(r, a1.z, d1); d2 = fmaf(r, a2.z, d2);
    r = elu1(w.w * s.w); rn2 = fmaf(r, r, rn2); d0 = fmaf(r, a0.w, d0); d1 = fmaf(r, a1.w, d1); d2 = fmaf(r, a2.w, d2);
}

// One wave per row (R2-fast form). Lane l owns cols [4l,4l+4) and
// [256+4l,256+4l+4): weight + 3 ave rows in registers; butterfly reduce;
// lanes 0..2 write the softmax row.
__global__ __launch_bounds__(256) void cosine_softmax_kernel(
        const float* __restrict__ seq, const float* __restrict__ weight,
        const float* __restrict__ ave, const float* __restrict__ an3,
        float* __restrict__ out) {
    const int lane = threadIdx.x & 63;
    const int wv = threadIdx.x >> 6;
    const int b0 = 4 * lane, b1 = 256 + 4 * lane;
    const float4 w0 = *(const float4*)(weight + b0);
    const float4 w1 = *(const float4*)(weight + b1);
    const float4 a00 = *(const float4*)(ave + 0 * DCOLS + b0);
    const float4 a01 = *(const float4*)(ave + 0 * DCOLS + b1);
    const float4 a10 = *(const float4*)(ave + 1 * DCOLS + b0);
    const float4 a11 = *(const float4*)(ave + 1 * DCOLS + b1);
    const float4 a20 = *(const float4*)(ave + 2 * DCOLS + b0);
    const float4 a21 = *(const float4*)(ave + 2 * DCOLS + b1);
    const float an0 = an3[0], an1 = an3[1], an2 = an3[2];
    for (int row = blockIdx.x * 4 + wv; row < NROWS; row += CGRID * 4) {
        const float* srow = seq + (size_t)row * DCOLS;
        float4 s0 = *(const float4*)(srow + b0);
        float4 s1 = *(const float4*)(srow + b1);
        float rn2 = 0.f, d0 = 0.f, d1 = 0.f, d2 = 0.f;
        proc4(s0, w0, a00, a10, a20, rn2, d0, d1, d2);
        proc4(s1, w1, a01, a11, a21, rn2, d0, d1, d2);
        #pragma unroll
        for (int o = 32; o; o >>= 1) {
            rn2 += __shfl_xor(rn2, o);
            d0  += __shfl_xor(d0, o);
            d1  += __shfl_xor(d1, o);
            d2  += __shfl_xor(d2, o);
        }
        if (lane < 3) {
            const float rn = sqrtf(rn2);
            float s0v = d0 / fmaxf(rn * an0, 1e-8f);
            float s1v = d1 / fmaxf(rn * an1, 1e-8f);
            float s2v = d2 / fmaxf(rn * an2, 1e-8f);
            float m = fmaxf(s0v, fmaxf(s1v, s2v));
            float e0 = __expf(s0v - m), e1 = __expf(s1v - m), e2 = __expf(s2v - m);
            float inv = 1.0f / (e0 + e1 + e2);
            float p = (lane == 0) ? e0 : (lane == 1 ? e1 : e2);
            out[(size_t)row * 3 + lane] = p * inv;
        }
    }
}

extern "C" void kernel_launch(void* const* d_in, const int* in_sizes, int n_in,
                              void* d_out, int out_size, void* d_ws, size_t ws_size,
                              hipStream_t stream) {
    const float* seq     = (const float*)d_in[0];
    const float* feature = (const float*)d_in[1];
    const int*   labels  = (const int*)d_in[2];
    const float* weight  = (const float*)d_in[3];
    const int*   train   = (const int*)d_in[4];
    float* out = (float*)d_out;

    float* sums = (float*)d_ws;           // 1536 floats
    float* ave  = sums + NC * DCOLS;      // 1536 floats
    float* an   = ave + NC * DCOLS;       // 3 floats

    zero_sums<<<6, 256, 0, stream>>>(sums);
    segsum_kernel<<<SGRID, 256, 0, stream>>>(feature, seq, weight, labels, train, sums);
    ave_norm_kernel<<<1, 256, 0, stream>>>(sums, ave, an);
    cosine_softmax_kernel<<<CGRID, 256, 0, stream>>>(seq, weight, ave, an, out);
}

// Round 5
// 224.792 us; speedup vs baseline: 1.5212x; 1.5212x over previous
//
#include <hip/hip_runtime.h>
#include <math.h>

#define NROWS 200000
#define DCOLS 512
#define NC 3
#define SGRID 1024
#define RPS (SGRID * 32)   // rows per grid step (32/block: 16 per half)
#define NFULL 196608       // 6 * RPS
#define TAILB 106          // (NROWS-NFULL)/32 blocks cover tail exactly
#define CGRID 2048

typedef float f4 __attribute__((ext_vector_type(4)));

__device__ __forceinline__ float elu1(float x) {
    return x > 0.0f ? x : __expf(x) - 1.0f;
}

__global__ void zero_sums(float* sums) {
    int t = blockIdx.x * blockDim.x + threadIdx.x;
    if (t < NC * DCOLS) sums[t] = 0.0f;
}

// 16 independent rows in flight per thread (64 load VGPRs). Labels first,
// then a burst of 16 global_load_dwordx4 (addresses independent), then the
// wave-uniform accumulate branches. This is the MLP the miss-queue needs.
#define BODY16(base)                                                         \
    {                                                                        \
        int lb[16]; f4 v[16];                                                \
        _Pragma("unroll") for (int j = 0; j < 16; ++j)                       \
            lb[j] = labels[(base) + 2 * j];                                  \
        _Pragma("unroll") for (int j = 0; j < 16; ++j)                       \
            v[j] = *(const f4*)(pbase + (size_t)((base) + 2 * j) * DCOLS);   \
        _Pragma("unroll") for (int j = 0; j < 16; ++j) {                     \
            f4 x = v[j];                                                     \
            if (tr) { x.x = elu1(w.x * x.x); x.y = elu1(w.y * x.y);          \
                      x.z = elu1(w.z * x.z); x.w = elu1(w.w * x.w); }        \
            if (lb[j] == 0)      a0 += x;                                    \
            else if (lb[j] == 1) a1 += x;                                    \
            else                 a2 += x;                                    \
        }                                                                    \
    }

__global__ __launch_bounds__(256) void segsum_kernel(
        const float* __restrict__ feature, const float* __restrict__ seq,
        const float* __restrict__ weight, const int* __restrict__ labels,
        const int* __restrict__ train, float* __restrict__ sums) {
    const int t = threadIdx.x;
    const int c4 = (t & 127) << 2;   // column base (4 floats)
    const int h  = t >> 7;           // wave-uniform row parity
    const int tr = train[0];
    f4 w = (f4)(0.f);
    if (tr) w = *(const f4*)(weight + c4);
    const float* __restrict__ src = tr ? seq : feature;
    const float* pbase = src + c4;
    f4 a0 = (f4)(0.f), a1 = (f4)(0.f), a2 = (f4)(0.f);

    // rows for this half: base, base+2, ..., base+30 within a 32-row block
    for (int base = blockIdx.x * 32 + h; base < NFULL; base += RPS)
        BODY16(base);
    if (blockIdx.x < TAILB)
        BODY16(NFULL + blockIdx.x * 32 + h);

    // halves-reduce in LDS, then one atomicAdd per (class,col) per block
    __shared__ float red[NC][128][4];
    if (h == 1) {
        const int c = t & 127;
        *(f4*)red[0][c] = a0;
        *(f4*)red[1][c] = a1;
        *(f4*)red[2][c] = a2;
    }
    __syncthreads();
    if (h == 0) {
        const int c = t;
        a0 += *(const f4*)red[0][c];
        a1 += *(const f4*)red[1][c];
        a2 += *(const f4*)red[2][c];
        atomicAdd(&sums[0 * DCOLS + c4 + 0], a0.x);
        atomicAdd(&sums[0 * DCOLS + c4 + 1], a0.y);
        atomicAdd(&sums[0 * DCOLS + c4 + 2], a0.z);
        atomicAdd(&sums[0 * DCOLS + c4 + 3], a0.w);
        atomicAdd(&sums[1 * DCOLS + c4 + 0], a1.x);
        atomicAdd(&sums[1 * DCOLS + c4 + 1], a1.y);
        atomicAdd(&sums[1 * DCOLS + c4 + 2], a1.z);
        atomicAdd(&sums[1 * DCOLS + c4 + 3], a1.w);
        atomicAdd(&sums[2 * DCOLS + c4 + 0], a2.x);
        atomicAdd(&sums[2 * DCOLS + c4 + 1], a2.y);
        atomicAdd(&sums[2 * DCOLS + c4 + 2], a2.z);
        atomicAdd(&sums[2 * DCOLS + c4 + 3], a2.w);
    }
}

// ave = sums / (N/2); an[c] = ||ave[c]||. Single block.
__global__ __launch_bounds__(256) void ave_norm_kernel(
        const float* __restrict__ sums, float* __restrict__ ave,
        float* __restrict__ an) {
    __shared__ float red[4];
    const int t = threadIdx.x, lane = t & 63, wv = t >> 6;
    const float inv = 1.0f / (float)(NROWS / 2);
    for (int c = 0; c < NC; ++c) {
        float p = 0.0f;
        for (int j = t; j < DCOLS; j += 256) {
            float v = sums[c * DCOLS + j] * inv;
            ave[c * DCOLS + j] = v;
            p += v * v;
        }
        for (int o = 32; o; o >>= 1) p += __shfl_xor(p, o);
        if (lane == 0) red[wv] = p;
        __syncthreads();
        if (t == 0) an[c] = sqrtf(red[0] + red[1] + red[2] + red[3]);
        __syncthreads();
    }
}

__device__ __forceinline__ void proc4(float4 s, float4 w,
                                      float4 a0, float4 a1, float4 a2,
                                      float& rn2, float& d0, float& d1, float& d2) {
    float r;
    r = elu1(w.x * s.x); rn2 = fmaf(r, r, rn2); d0 = fmaf(r, a0.x, d0); d1 = fmaf(r, a1.x, d1); d2 = fmaf(r, a2.x, d2);
    r = elu1(w.y * s.y); rn2 = fmaf(r, r, rn2); d0 = fmaf(r, a0.y, d0); d1 = fmaf(r, a1.y, d1); d2 = fmaf(r, a2.y, d2);
    r = elu1(w.z * s.z); rn2 = fmaf(r, r, rn2); d0 = fmaf(r, a0.z, d0); d1 = fmaf(r, a1.z, d1); d2 = fmaf(r, a2.z, d2);
    r = elu1(w.w * s.w); rn2 = fmaf(r, r, rn2); d0 = fmaf(r, a0.w, d0); d1 = fmaf(r, a1.w, d1); d2 = fmaf(r, a2.w, d2);
}

// One wave per row (R1-fast form). Lane l owns cols [4l,4l+4) and
// [256+4l,256+4l+4): weight + 3 ave rows in registers; butterfly reduce;
// lanes 0..2 write the softmax row.
__global__ __launch_bounds__(256) void cosine_softmax_kernel(
        const float* __restrict__ seq, const float* __restrict__ weight,
        const float* __restrict__ ave, const float* __restrict__ an3,
        float* __restrict__ out) {
    const int lane = threadIdx.x & 63;
    const int wv = threadIdx.x >> 6;
    const int b0 = 4 * lane, b1 = 256 + 4 * lane;
    const float4 w0 = *(const float4*)(weight + b0);
    const float4 w1 = *(const float4*)(weight + b1);
    const float4 a00 = *(const float4*)(ave + 0 * DCOLS + b0);
    const float4 a01 = *(const float4*)(ave + 0 * DCOLS + b1);
    const float4 a10 = *(const float4*)(ave + 1 * DCOLS + b0);
    const float4 a11 = *(const float4*)(ave + 1 * DCOLS + b1);
    const float4 a20 = *(const float4*)(ave + 2 * DCOLS + b0);
    const float4 a21 = *(const float4*)(ave + 2 * DCOLS + b1);
    const float an0 = an3[0], an1 = an3[1], an2 = an3[2];
    for (int row = blockIdx.x * 4 + wv; row < NROWS; row += CGRID * 4) {
        const float* srow = seq + (size_t)row * DCOLS;
        float4 s0 = *(const float4*)(srow + b0);
        float4 s1 = *(const float4*)(srow + b1);
        float rn2 = 0.f, d0 = 0.f, d1 = 0.f, d2 = 0.f;
        proc4(s0, w0, a00, a10, a20, rn2, d0, d1, d2);
        proc4(s1, w1, a01, a11, a21, rn2, d0, d1, d2);
        #pragma unroll
        for (int o = 32; o; o >>= 1) {
            rn2 += __shfl_xor(rn2, o);
            d0  += __shfl_xor(d0, o);
            d1  += __shfl_xor(d1, o);
            d2  += __shfl_xor(d2, o);
        }
        if (lane < 3) {
            const float rn = sqrtf(rn2);
            float s0v = d0 / fmaxf(rn * an0, 1e-8f);
            float s1v = d1 / fmaxf(rn * an1, 1e-8f);
            float s2v = d2 / fmaxf(rn * an2, 1e-8f);
            float m = fmaxf(s0v, fmaxf(s1v, s2v));
            float e0 = __expf(s0v - m), e1 = __expf(s1v - m), e2 = __expf(s2v - m);
            float inv = 1.0f / (e0 + e1 + e2);
            float p = (lane == 0) ? e0 : (lane == 1 ? e1 : e2);
            out[(size_t)row * 3 + lane] = p * inv;
        }
    }
}

extern "C" void kernel_launch(void* const* d_in, const int* in_sizes, int n_in,
                              void* d_out, int out_size, void* d_ws, size_t ws_size,
                              hipStream_t stream) {
    const float* seq     = (const float*)d_in[0];
    const float* feature = (const float*)d_in[1];
    const int*   labels  = (const int*)d_in[2];
    const float* weight  = (const float*)d_in[3];
    const int*   train   = (const int*)d_in[4];
    float* out = (float*)d_out;

    float* sums = (float*)d_ws;           // 1536 floats
    float* ave  = sums + NC * DCOLS;      // 1536 floats
    float* an   = ave + NC * DCOLS;       // 3 floats

    zero_sums<<<6, 256, 0, stream>>>(sums);
    segsum_kernel<<<SGRID, 256, 0, stream>>>(feature, seq, weight, labels, train, sums);
    ave_norm_kernel<<<1, 256, 0, stream>>>(sums, ave, an);
    cosine_softmax_kernel<<<CGRID, 256, 0, stream>>>(seq, weight, ave, an, out);
}